// Round 13
// baseline (257.789 us; speedup 1.0000x reference)
//
#include <hip/hip_runtime.h>

#define E_EDGES 131072
// Layer dims: in {2048,4096,4096} -> out {4096,4096,1024}, batch 1024.
// Activations feature-major (hT[feat][1024]); CSR-by-dst built on device with
// no global atomics (LDS histogram -> scan -> LDS-cursor scatter).
// Rows padded to multiples of 8 (zero pads written inline by scan_kernel).
// SpMM (r11 streaming form, best measured): wave owns rpw consecutive rows,
// walks their contiguous padded CSR range as one scalar-prefetched stream;
// float4 gathers (1 KB/instr), 256-col chunks, c = blockIdx&3.
// r13 change: C_CH 16 -> 64 with chunk-major cntA[l][c][4096] so the CSR
// build uses 192 blocks (was 48) with fully-coalesced private stores.

#define EPAD01 163840   // capacity, layers 0,1 (4096 rows, E + 8*rows)
#define EPAD2  139264   // capacity, layer 2  (1024 rows)
#define C_CH   64       // chunks per layer (preprocessing)
#define CHUNK  (E_EDGES / C_CH)   // 2048 edges per chunk

typedef int iv4 __attribute__((ext_vector_type(4)));

// cntA index: [l][c][row], contiguous per (l,c) block.
#define CIDX(L, C, R) ((((L) << 6) + (C)) * 4096 + (R))

// K1: fused transpose of x (blocks 0..2047) + dst histogram (blocks 2048..2048+191).
__global__ void __launch_bounds__(256) fused_tp_count_kernel(
    const float* __restrict__ x, float* __restrict__ xT,
    const int* __restrict__ d0, const int* __restrict__ d1, const int* __restrict__ d2,
    int* __restrict__ cntA) {
  __shared__ int sh[4096];
  int bid = blockIdx.x;
  int t = threadIdx.x;
  if (bid < 2048) {
    float (*tile)[33] = (float(*)[33])sh;
    int c0 = (bid & 63) << 5, r0 = (bid >> 6) << 5;
    int tx = t & 31, ty = t >> 5;  // 32 x 8
#pragma unroll
    for (int i = 0; i < 32; i += 8)
      tile[ty + i][tx] = x[(size_t)(r0 + ty + i) * 2048 + (c0 + tx)];
    __syncthreads();
#pragma unroll
    for (int i = 0; i < 32; i += 8)
      xT[(size_t)(c0 + ty + i) * 1024 + (r0 + tx)] = tile[tx][ty + i];
  } else {
    int bid2 = bid - 2048, l = bid2 >> 6, c = bid2 & 63;
    const int* dp = (l == 0) ? d0 : (l == 1) ? d1 : d2;
    for (int r = t; r < 4096; r += 256) sh[r] = 0;
    __syncthreads();
    int base = c * CHUNK;
    for (int i = 0; i < CHUNK; i += 256)
      atomicAdd(&sh[dp[base + i + t]], 1);
    __syncthreads();
    for (int r = t; r < 4096; r += 256)
      cntA[CIDX(l, c, r)] = sh[r];  // layer2 rows>=1024 stay 0
  }
}

// K2: per-layer (blockIdx = l) padded row scan + inline pad-slot zeroing.
// rowptr[row] = padded row start; cntA[l][c][row] -> chunk start offsets.
__global__ void __launch_bounds__(1024) scan_kernel(int* __restrict__ cntA,
                                                    int* __restrict__ rowptr,
                                                    int2* __restrict__ edges) {
  int l = blockIdx.x;
  int* rp = rowptr + l * 4104;
  int off = (l == 0) ? 0 : (l == 1) ? EPAD01 : 2 * EPAD01;
  int t = threadIdx.x;  // 1024 threads, 4 rows each
  int tot[4], pad[4];
  int local = 0;
  for (int i = 0; i < 4; ++i) {
    int row = (t << 2) + i;
    int s = 0;
    for (int c = 0; c < C_CH; ++c) s += cntA[CIDX(l, c, row)];
    tot[i] = s;
    pad[i] = (s + 7) & ~7;   // pad row to multiple of 8 (8-edge groups)
    local += pad[i];
  }
  int lane = t & 63, wid = t >> 6;
  int incl = local;
  for (int o = 1; o < 64; o <<= 1) {
    int u = __shfl_up(incl, o, 64);
    if (lane >= o) incl += u;
  }
  __shared__ int wsum[16];
  if (lane == 63) wsum[wid] = incl;
  __syncthreads();
  if (t < 16) {
    int v = wsum[t];
    int iv = v;
    for (int o = 1; o < 16; o <<= 1) {
      int u = __shfl_up(iv, o, 16);
      if (t >= o) iv += u;
    }
    wsum[t] = iv - v;
  }
  __syncthreads();
  int run = wsum[wid] + (incl - local);
  int2 z = make_int2(0, 0);
  for (int i = 0; i < 4; ++i) {
    int row = (t << 2) + i;
    rp[row] = run;
    int acc = run;
    for (int c = 0; c < C_CH; ++c) {
      int v = cntA[CIDX(l, c, row)];
      cntA[CIDX(l, c, row)] = acc;
      acc += v;
    }
    for (int q = run + tot[i]; q < run + pad[i]; ++q) edges[off + q] = z;  // pads
    run += pad[i];
  }
  if (t == 1023) rp[4096] = run;  // rows past n are 0-count; also covers rp[n]
}

// K3: scatter with LDS cursors only. bid = l*64 + c.
__global__ void __launch_bounds__(256) scatter_kernel(
    const int* __restrict__ s0p, const int* __restrict__ d0p, const float* __restrict__ w0p,
    const int* __restrict__ s1p, const int* __restrict__ d1p, const float* __restrict__ w1p,
    const int* __restrict__ s2p, const int* __restrict__ d2p, const float* __restrict__ w2p,
    const int* __restrict__ cntA, int2* __restrict__ edges) {
  int bid = blockIdx.x, l = bid >> 6, c = bid & 63;
  const int* sp = (l == 0) ? s0p : (l == 1) ? s1p : s2p;
  const int* dp = (l == 0) ? d0p : (l == 1) ? d1p : d2p;
  const float* wp = (l == 0) ? w0p : (l == 1) ? w1p : w2p;
  int off = (l == 0) ? 0 : (l == 1) ? EPAD01 : 2 * EPAD01;
  __shared__ int cursor[4096];
  for (int r = threadIdx.x; r < 4096; r += 256)
    cursor[r] = cntA[CIDX(l, c, r)];
  __syncthreads();
  int base = c * CHUNK;
  for (int i = 0; i < CHUNK; i += 256) {
    int e = base + i + threadIdx.x;
    int d = dp[e];
    int s = sp[e];
    float wv = wp[e];
    int pos = atomicAdd(&cursor[d], 1);
    edges[off + pos] = make_int2(s, __float_as_int(wv));
  }
}

#define LD4(IDX) (*(const float4*)(hb + ((size_t)(unsigned)(IDX) << 12)))
#define FMA4(A, WB, V) { float _w = __int_as_float(WB); \
  A.x = fmaf(_w, V.x, A.x); A.y = fmaf(_w, V.y, A.y); \
  A.z = fmaf(_w, V.z, A.z); A.w = fmaf(_w, V.w, A.w); }
#define STORE_ROW(RR, O) *(float4*)((char*)outT + (((size_t)(RR) << 12) + ((size_t)col << 2))) = (O)

// SpMM (r11 form): 128-thread block = 2 waves; wave owns rpw consecutive rows
// and streams their contiguous padded edge range (groups of 8; rows padded to
// 8 so groups never straddle rows). Edge metadata scalar (readfirstlane'd
// wave id -> uniform addresses); 8 float4 gathers in flight continuously.
__global__ void __launch_bounds__(128) spmm_kernel(const float* __restrict__ hT,
                                                   const int2* __restrict__ edges,
                                                   const int* __restrict__ rowptr,
                                                   const float* __restrict__ bias,
                                                   float* __restrict__ outT,
                                                   int rpw) {
  int c = blockIdx.x & 3;
  int rg = blockIdx.x >> 2;
  int w = __builtin_amdgcn_readfirstlane(threadIdx.x >> 6);
  int lane = threadIdx.x & 63;
  int r = (rg * 2 + w) * rpw;
  int rlim = r + rpw;
  int col = (c << 8) + (lane << 2);
  const char* hb = (const char*)(hT + col);

  int e = rowptr[r];
  int e_last = rowptr[rlim];
  int r_end = 0;
  for (;;) {
    if (r >= rlim) break;
    r_end = rowptr[r + 1];
    if (r_end != e) break;
    float bb = bias[r];
    float4 o; o.x = o.y = o.z = o.w = fmaxf(bb, 0.f);
    STORE_ROW(r, o);
    ++r;
  }
  if (e >= e_last) return;

  const iv4* ep = (const iv4*)(edges + e);
  iv4 q0 = ep[0], q1 = ep[1], q2 = ep[2], q3 = ep[3];
  float4 a0 = {0.f, 0.f, 0.f, 0.f}, a1 = {0.f, 0.f, 0.f, 0.f};
  while (e < e_last) {
    iv4 p0 = q0, p1 = q1, p2 = q2, p3 = q3;
    ep += 4;
    // prefetch next group; may read <=32B past e_last, inside edges capacity
    q0 = ep[0]; q1 = ep[1]; q2 = ep[2]; q3 = ep[3];
    float4 v0 = LD4(p0.x), v1 = LD4(p0.z), v2 = LD4(p1.x), v3 = LD4(p1.z);
    float4 v4 = LD4(p2.x), v5 = LD4(p2.z), v6 = LD4(p3.x), v7 = LD4(p3.z);
    FMA4(a0, p0.y, v0); FMA4(a1, p0.w, v1);
    FMA4(a0, p1.y, v2); FMA4(a1, p1.w, v3);
    FMA4(a0, p2.y, v4); FMA4(a1, p2.w, v5);
    FMA4(a0, p3.y, v6); FMA4(a1, p3.w, v7);
    e += 8;
    if (e == r_end) {   // group boundary == row boundary (rows padded to 8)
      float bb = bias[r];
      float4 o;
      o.x = fmaxf((a0.x + a1.x) + bb, 0.f);
      o.y = fmaxf((a0.y + a1.y) + bb, 0.f);
      o.z = fmaxf((a0.z + a1.z) + bb, 0.f);
      o.w = fmaxf((a0.w + a1.w) + bb, 0.f);
      STORE_ROW(r, o);
      a0.x = a0.y = a0.z = a0.w = 0.f;
      a1.x = a1.y = a1.z = a1.w = 0.f;
      ++r;
      for (;;) {
        if (r >= rlim) break;
        r_end = rowptr[r + 1];
        if (r_end != e) break;
        float b2 = bias[r];
        float4 o2; o2.x = o2.y = o2.z = o2.w = fmaxf(b2, 0.f);
        STORE_ROW(r, o2);
        ++r;
      }
    }
  }
}

__global__ void transpose_kernel(const float* __restrict__ in, float* __restrict__ out,
                                 int R, int C) {
  __shared__ float tile[32][33];
  int c0 = blockIdx.x << 5, r0 = blockIdx.y << 5;
  int tx = threadIdx.x, ty = threadIdx.y;  // 32 x 8
#pragma unroll
  for (int i = 0; i < 32; i += 8)
    tile[ty + i][tx] = in[(size_t)(r0 + ty + i) * C + (c0 + tx)];
  __syncthreads();
#pragma unroll
  for (int i = 0; i < 32; i += 8)
    out[(size_t)(c0 + ty + i) * R + (r0 + tx)] = tile[tx][ty + i];
}

extern "C" void kernel_launch(void* const* d_in, const int* in_sizes, int n_in,
                              void* d_out, int out_size, void* d_ws, size_t ws_size,
                              hipStream_t stream) {
  const float* x = (const float*)d_in[0];
  const int* src[3]    = {(const int*)d_in[1], (const int*)d_in[5], (const int*)d_in[9]};
  const int* dst[3]    = {(const int*)d_in[2], (const int*)d_in[6], (const int*)d_in[10]};
  const float* w[3]    = {(const float*)d_in[3], (const float*)d_in[7], (const float*)d_in[11]};
  const float* bias[3] = {(const float*)d_in[4], (const float*)d_in[8], (const float*)d_in[12]};
  float* out = (float*)d_out;

  // Workspace (~40 MB):
  //   buf0 @ 0          : 16 MB (xT, later h2T)
  //   buf1 @ 16 MB      : 16 MB (h1T, later outT)
  //   rowptr @ 32 MB    : 3*4104 ints
  //   cntA @ +64 KB     : 3*64*4096 ints = 3 MB (chunk-major counts/offsets)
  //   edges @ 36 MB     : (2*EPAD01+EPAD2) int2 = 3.6 MB, padded CSR
  char* ws = (char*)d_ws;
  float* buf0   = (float*)(ws);
  float* buf1   = (float*)(ws + (16u << 20));
  int*   rowptr = (int*)(ws + (32u << 20));
  int*   cntA   = (int*)(ws + (32u << 20) + 65536u);
  int2*  edges  = (int2*)(ws + (36u << 20));

  fused_tp_count_kernel<<<2048 + 3 * C_CH, 256, 0, stream>>>(
      x, buf0, dst[0], dst[1], dst[2], cntA);
  scan_kernel<<<3, 1024, 0, stream>>>(cntA, rowptr, edges);
  scatter_kernel<<<3 * C_CH, 256, 0, stream>>>(
      src[0], dst[0], w[0], src[1], dst[1], w[1], src[2], dst[2], w[2], cntA, edges);

  // layer 0: buf0 (2048x1024) -> buf1 (4096x1024), 2 rows/wave
  spmm_kernel<<<(4096 / 4) * 4, 128, 0, stream>>>(buf0, edges, rowptr, bias[0], buf1, 2);
  // layer 1: buf1 -> buf0 (4096x1024), 2 rows/wave
  spmm_kernel<<<(4096 / 4) * 4, 128, 0, stream>>>(buf1, edges + EPAD01, rowptr + 4104, bias[1], buf0, 2);
  // layer 2: buf0 -> buf1 (1024x1024, outT), 1 row/wave
  spmm_kernel<<<(1024 / 2) * 4, 128, 0, stream>>>(buf0, edges + 2 * EPAD01, rowptr + 2 * 4104, bias[2], buf1, 1);

  // outT [1024 dst][1024 batch] -> d_out [batch][dst]
  transpose_kernel<<<dim3(1024 / 32, 1024 / 32), dim3(32, 8), 0, stream>>>(buf1, out, 1024, 1024);
}

// Round 14
// 114.296 us; speedup vs baseline: 2.2555x; 2.2555x over previous
//
#include <hip/hip_runtime.h>

#define E_EDGES 131072
// Layer dims: in {2048,4096,4096} -> out {4096,4096,1024}, batch 1024.
// Activations feature-major (hT[feat][1024]); CSR-by-dst built on device with
// no global atomics. Chunk-major cntA[l][c][row] (coalesced count/scatter);
// scan split into rowprefix (48 blocks, coalesced) + tiny row scan (r13
// post-mortem: single-kernel scan over chunk-major was 3-block latency-bound).
// Rows padded to multiples of 8 (zero pads written inline by scan_kernel).
// SpMM (r11 streaming form, best measured): wave owns rpw consecutive rows,
// walks their contiguous padded CSR range as one scalar-prefetched stream;
// float4 gathers (1 KB/instr), 256-col chunks, c = blockIdx&3.

#define EPAD01 163840   // capacity, layers 0,1 (4096 rows, E + 8*rows)
#define EPAD2  139264   // capacity, layer 2  (1024 rows)
#define C_CH   64       // chunks per layer (preprocessing)
#define CHUNK  (E_EDGES / C_CH)   // 2048 edges per chunk

typedef int iv4 __attribute__((ext_vector_type(4)));

// cntA index: [l][c][row], contiguous per (l,c) block.
#define CIDX(L, C, R) ((((L) << 6) + (C)) * 4096 + (R))

// K1: fused transpose of x (blocks 0..2047) + dst histogram (blocks 2048..2239).
__global__ void __launch_bounds__(256) fused_tp_count_kernel(
    const float* __restrict__ x, float* __restrict__ xT,
    const int* __restrict__ d0, const int* __restrict__ d1, const int* __restrict__ d2,
    int* __restrict__ cntA) {
  __shared__ int sh[4096];
  int bid = blockIdx.x;
  int t = threadIdx.x;
  if (bid < 2048) {
    float (*tile)[33] = (float(*)[33])sh;
    int c0 = (bid & 63) << 5, r0 = (bid >> 6) << 5;
    int tx = t & 31, ty = t >> 5;  // 32 x 8
#pragma unroll
    for (int i = 0; i < 32; i += 8)
      tile[ty + i][tx] = x[(size_t)(r0 + ty + i) * 2048 + (c0 + tx)];
    __syncthreads();
#pragma unroll
    for (int i = 0; i < 32; i += 8)
      xT[(size_t)(c0 + ty + i) * 1024 + (r0 + tx)] = tile[tx][ty + i];
  } else {
    int bid2 = bid - 2048, l = bid2 >> 6, c = bid2 & 63;
    const int* dp = (l == 0) ? d0 : (l == 1) ? d1 : d2;
    for (int r = t; r < 4096; r += 256) sh[r] = 0;
    __syncthreads();
    int base = c * CHUNK;
    for (int i = 0; i < CHUNK; i += 256)
      atomicAdd(&sh[dp[base + i + t]], 1);
    __syncthreads();
    for (int r = t; r < 4096; r += 256)
      cntA[CIDX(l, c, r)] = sh[r];  // layer2 rows>=1024 stay 0
  }
}

// K2a: within-row exclusive prefix over chunks, in place; emits row totals.
// 48 blocks x 256; thread = one row; for fixed c consecutive threads read
// consecutive rows -> coalesced.
__global__ void __launch_bounds__(256) rowprefix_kernel(int* __restrict__ cntA,
                                                        int* __restrict__ rowTot) {
  int l = blockIdx.x >> 4;          // 16 blocks per layer
  int rg = blockIdx.x & 15;
  int row = (rg << 8) + threadIdx.x;
  int acc = 0;
#pragma unroll 4
  for (int c = 0; c < C_CH; ++c) {
    int idx = CIDX(l, c, row);
    int v = cntA[idx];
    cntA[idx] = acc;                // within-row exclusive prefix
    acc += v;
  }
  rowTot[(l << 12) + row] = acc;
}

// K2b: per-layer (blockIdx = l) padded row scan + inline pad-slot zeroing.
__global__ void __launch_bounds__(1024) scan_kernel(const int* __restrict__ rowTot,
                                                    int* __restrict__ rowptr,
                                                    int2* __restrict__ edges) {
  int l = blockIdx.x;
  int* rp = rowptr + l * 4104;
  int off = (l == 0) ? 0 : (l == 1) ? EPAD01 : 2 * EPAD01;
  int t = threadIdx.x;  // 1024 threads, 4 rows each
  int4 tt = *(const int4*)(rowTot + (l << 12) + (t << 2));
  int tot[4] = {tt.x, tt.y, tt.z, tt.w};
  int pad[4];
  int local = 0;
  for (int i = 0; i < 4; ++i) {
    pad[i] = (tot[i] + 7) & ~7;   // pad row to multiple of 8 (8-edge groups)
    local += pad[i];
  }
  int lane = t & 63, wid = t >> 6;
  int incl = local;
  for (int o = 1; o < 64; o <<= 1) {
    int u = __shfl_up(incl, o, 64);
    if (lane >= o) incl += u;
  }
  __shared__ int wsum[16];
  if (lane == 63) wsum[wid] = incl;
  __syncthreads();
  if (t < 16) {
    int v = wsum[t];
    int iv = v;
    for (int o = 1; o < 16; o <<= 1) {
      int u = __shfl_up(iv, o, 16);
      if (t >= o) iv += u;
    }
    wsum[t] = iv - v;
  }
  __syncthreads();
  int run = wsum[wid] + (incl - local);
  int2 z = make_int2(0, 0);
  for (int i = 0; i < 4; ++i) {
    int row = (t << 2) + i;
    rp[row] = run;
    for (int q = run + tot[i]; q < run + pad[i]; ++q) edges[off + q] = z;  // pads
    run += pad[i];
  }
  if (t == 1023) rp[4096] = run;  // rows past n are 0-count; also covers rp[n]
}

// K3: scatter with LDS cursors only. bid = l*64 + c.
// cursor = rowptr[r] (global row start) + cntA[l][c][r] (within-row prefix).
__global__ void __launch_bounds__(256) scatter_kernel(
    const int* __restrict__ s0p, const int* __restrict__ d0p, const float* __restrict__ w0p,
    const int* __restrict__ s1p, const int* __restrict__ d1p, const float* __restrict__ w1p,
    const int* __restrict__ s2p, const int* __restrict__ d2p, const float* __restrict__ w2p,
    const int* __restrict__ cntA, const int* __restrict__ rowptr,
    int2* __restrict__ edges) {
  int bid = blockIdx.x, l = bid >> 6, c = bid & 63;
  const int* sp = (l == 0) ? s0p : (l == 1) ? s1p : s2p;
  const int* dp = (l == 0) ? d0p : (l == 1) ? d1p : d2p;
  const float* wp = (l == 0) ? w0p : (l == 1) ? w1p : w2p;
  int off = (l == 0) ? 0 : (l == 1) ? EPAD01 : 2 * EPAD01;
  const int* rp = rowptr + l * 4104;
  __shared__ int cursor[4096];
  for (int r = threadIdx.x; r < 4096; r += 256)
    cursor[r] = rp[r] + cntA[CIDX(l, c, r)];
  __syncthreads();
  int base = c * CHUNK;
  for (int i = 0; i < CHUNK; i += 256) {
    int e = base + i + threadIdx.x;
    int d = dp[e];
    int s = sp[e];
    float wv = wp[e];
    int pos = atomicAdd(&cursor[d], 1);
    edges[off + pos] = make_int2(s, __float_as_int(wv));
  }
}

#define LD4(IDX) (*(const float4*)(hb + ((size_t)(unsigned)(IDX) << 12)))
#define FMA4(A, WB, V) { float _w = __int_as_float(WB); \
  A.x = fmaf(_w, V.x, A.x); A.y = fmaf(_w, V.y, A.y); \
  A.z = fmaf(_w, V.z, A.z); A.w = fmaf(_w, V.w, A.w); }
#define STORE_ROW(RR, O) *(float4*)((char*)outT + (((size_t)(RR) << 12) + ((size_t)col << 2))) = (O)

// SpMM (r11 form): 128-thread block = 2 waves; wave owns rpw consecutive rows
// and streams their contiguous padded edge range (groups of 8; rows padded to
// 8 so groups never straddle rows). Edge metadata scalar (readfirstlane'd
// wave id -> uniform addresses); 8 float4 gathers in flight continuously.
__global__ void __launch_bounds__(128) spmm_kernel(const float* __restrict__ hT,
                                                   const int2* __restrict__ edges,
                                                   const int* __restrict__ rowptr,
                                                   const float* __restrict__ bias,
                                                   float* __restrict__ outT,
                                                   int rpw) {
  int c = blockIdx.x & 3;
  int rg = blockIdx.x >> 2;
  int w = __builtin_amdgcn_readfirstlane(threadIdx.x >> 6);
  int lane = threadIdx.x & 63;
  int r = (rg * 2 + w) * rpw;
  int rlim = r + rpw;
  int col = (c << 8) + (lane << 2);
  const char* hb = (const char*)(hT + col);

  int e = rowptr[r];
  int e_last = rowptr[rlim];
  int r_end = 0;
  for (;;) {
    if (r >= rlim) break;
    r_end = rowptr[r + 1];
    if (r_end != e) break;
    float bb = bias[r];
    float4 o; o.x = o.y = o.z = o.w = fmaxf(bb, 0.f);
    STORE_ROW(r, o);
    ++r;
  }
  if (e >= e_last) return;

  const iv4* ep = (const iv4*)(edges + e);
  iv4 q0 = ep[0], q1 = ep[1], q2 = ep[2], q3 = ep[3];
  float4 a0 = {0.f, 0.f, 0.f, 0.f}, a1 = {0.f, 0.f, 0.f, 0.f};
  while (e < e_last) {
    iv4 p0 = q0, p1 = q1, p2 = q2, p3 = q3;
    ep += 4;
    // prefetch next group; may read <=32B past e_last, inside edges capacity
    q0 = ep[0]; q1 = ep[1]; q2 = ep[2]; q3 = ep[3];
    float4 v0 = LD4(p0.x), v1 = LD4(p0.z), v2 = LD4(p1.x), v3 = LD4(p1.z);
    float4 v4 = LD4(p2.x), v5 = LD4(p2.z), v6 = LD4(p3.x), v7 = LD4(p3.z);
    FMA4(a0, p0.y, v0); FMA4(a1, p0.w, v1);
    FMA4(a0, p1.y, v2); FMA4(a1, p1.w, v3);
    FMA4(a0, p2.y, v4); FMA4(a1, p2.w, v5);
    FMA4(a0, p3.y, v6); FMA4(a1, p3.w, v7);
    e += 8;
    if (e == r_end) {   // group boundary == row boundary (rows padded to 8)
      float bb = bias[r];
      float4 o;
      o.x = fmaxf((a0.x + a1.x) + bb, 0.f);
      o.y = fmaxf((a0.y + a1.y) + bb, 0.f);
      o.z = fmaxf((a0.z + a1.z) + bb, 0.f);
      o.w = fmaxf((a0.w + a1.w) + bb, 0.f);
      STORE_ROW(r, o);
      a0.x = a0.y = a0.z = a0.w = 0.f;
      a1.x = a1.y = a1.z = a1.w = 0.f;
      ++r;
      for (;;) {
        if (r >= rlim) break;
        r_end = rowptr[r + 1];
        if (r_end != e) break;
        float b2 = bias[r];
        float4 o2; o2.x = o2.y = o2.z = o2.w = fmaxf(b2, 0.f);
        STORE_ROW(r, o2);
        ++r;
      }
    }
  }
}

__global__ void transpose_kernel(const float* __restrict__ in, float* __restrict__ out,
                                 int R, int C) {
  __shared__ float tile[32][33];
  int c0 = blockIdx.x << 5, r0 = blockIdx.y << 5;
  int tx = threadIdx.x, ty = threadIdx.y;  // 32 x 8
#pragma unroll
  for (int i = 0; i < 32; i += 8)
    tile[ty + i][tx] = in[(size_t)(r0 + ty + i) * C + (c0 + tx)];
  __syncthreads();
#pragma unroll
  for (int i = 0; i < 32; i += 8)
    out[(size_t)(c0 + ty + i) * R + (r0 + tx)] = tile[tx][ty + i];
}

extern "C" void kernel_launch(void* const* d_in, const int* in_sizes, int n_in,
                              void* d_out, int out_size, void* d_ws, size_t ws_size,
                              hipStream_t stream) {
  const float* x = (const float*)d_in[0];
  const int* src[3]    = {(const int*)d_in[1], (const int*)d_in[5], (const int*)d_in[9]};
  const int* dst[3]    = {(const int*)d_in[2], (const int*)d_in[6], (const int*)d_in[10]};
  const float* w[3]    = {(const float*)d_in[3], (const float*)d_in[7], (const float*)d_in[11]};
  const float* bias[3] = {(const float*)d_in[4], (const float*)d_in[8], (const float*)d_in[12]};
  float* out = (float*)d_out;

  // Workspace (~40 MB):
  //   buf0 @ 0          : 16 MB (xT, later h2T)
  //   buf1 @ 16 MB      : 16 MB (h1T, later outT)
  //   rowptr @ 32 MB    : 3*4104 ints
  //   rowTot @ +64 KB   : 3*4096 ints
  //   cntA @ +128 KB    : 3*64*4096 ints = 3 MB (chunk-major)
  //   edges @ 36 MB     : (2*EPAD01+EPAD2) int2 = 3.6 MB, padded CSR
  char* ws = (char*)d_ws;
  float* buf0   = (float*)(ws);
  float* buf1   = (float*)(ws + (16u << 20));
  int*   rowptr = (int*)(ws + (32u << 20));
  int*   rowTot = (int*)(ws + (32u << 20) + 65536u);
  int*   cntA   = (int*)(ws + (32u << 20) + 131072u);
  int2*  edges  = (int2*)(ws + (36u << 20));

  fused_tp_count_kernel<<<2048 + 3 * C_CH, 256, 0, stream>>>(
      x, buf0, dst[0], dst[1], dst[2], cntA);
  rowprefix_kernel<<<48, 256, 0, stream>>>(cntA, rowTot);
  scan_kernel<<<3, 1024, 0, stream>>>(rowTot, rowptr, edges);
  scatter_kernel<<<3 * C_CH, 256, 0, stream>>>(
      src[0], dst[0], w[0], src[1], dst[1], w[1], src[2], dst[2], w[2],
      cntA, rowptr, edges);

  // layer 0: buf0 (2048x1024) -> buf1 (4096x1024), 2 rows/wave
  spmm_kernel<<<(4096 / 4) * 4, 128, 0, stream>>>(buf0, edges, rowptr, bias[0], buf1, 2);
  // layer 1: buf1 -> buf0 (4096x1024), 2 rows/wave
  spmm_kernel<<<(4096 / 4) * 4, 128, 0, stream>>>(buf1, edges + EPAD01, rowptr + 4104, bias[1], buf0, 2);
  // layer 2: buf0 -> buf1 (1024x1024, outT), 1 row/wave
  spmm_kernel<<<(1024 / 2) * 4, 128, 0, stream>>>(buf0, edges + 2 * EPAD01, rowptr + 2 * 4104, bias[2], buf1, 1);

  // outT [1024 dst][1024 batch] -> d_out [batch][dst]
  transpose_kernel<<<dim3(1024 / 32, 1024 / 32), dim3(32, 8), 0, stream>>>(buf1, out, 1024, 1024);
}